// Round 2
// baseline (1627.604 us; speedup 1.0000x reference)
//
#include <hip/hip_runtime.h>
#include <hip/hip_bf16.h>
#include <math.h>

// Problem constants (MambaStack reference)
#define DEPTH   2
#define DM      768      // d_model
#define DS      64       // d_state
#define DC      4        // d_conv
#define DI      1536     // d_inner
#define DTR     48       // dt_rank
#define BATCH   4
#define SEQ     2048
#define MROWS   (BATCH*SEQ)          // 8192
#define XDC     (DTR + 2*DS)         // 176 (xdbl cols)
#define NC      8                    // scan chunks
#define TCH     (SEQ/NC)             // 256 timesteps per chunk
#define LOG2E   1.44269504088896f

typedef __attribute__((ext_vector_type(8))) short bf16x8;
typedef __attribute__((ext_vector_type(4))) float f32x4;
typedef unsigned short ushort_t;
#define GAS __attribute__((address_space(1)))
#define LAS __attribute__((address_space(3)))

__device__ __forceinline__ float silu_fast(float x) {
    return x / (1.f + __expf(-x));
}
__device__ __forceinline__ float softplus_acc(float x) {
    return x > 20.f ? x : log1pf(expf(x));
}

// Split fp32 -> (hi, lo) bf16 pair, both RNE.  hi+lo represents f to ~2^-17.
__device__ __forceinline__ void bf16_split(float f, ushort_t& h, ushort_t& l) {
    unsigned u = __float_as_uint(f);
    unsigned hr = u + 0x7FFF + ((u >> 16) & 1);
    h = (ushort_t)(hr >> 16);
    float lof = f - __uint_as_float((unsigned)h << 16);
    unsigned ul = __float_as_uint(lof);
    unsigned lr = ul + 0x7FFF + ((ul >> 16) & 1);
    l = (ushort_t)(lr >> 16);
}

// Contiguous fp32 array -> hi/lo bf16 planes.  n multiple of 1024.
__global__ __launch_bounds__(256) void split_bf16(
    const float* __restrict__ in, ushort_t* __restrict__ hi,
    ushort_t* __restrict__ lo)
{
    const size_t i = ((size_t)blockIdx.x * 256 + threadIdx.x) * 4;
    const float4 v = *(const float4*)(in + i);
    ushort4 h, l;
    bf16_split(v.x, h.x, l.x); bf16_split(v.y, h.y, l.y);
    bf16_split(v.z, h.z, l.z); bf16_split(v.w, h.w, l.w);
    *(ushort4*)(hi + i) = h;
    *(ushort4*)(lo + i) = l;
}

// ---------------- bf16x2-split MFMA GEMM ----------------
// C[M,N] = (Ah+Al) @ (Wh+Wl)^T, planes bf16, row strides ldA/ldW (elements).
// 128x128 tile, BK=32, 4 waves; 16x16x32 MFMA, 3 per tile (hh, hl, lh).
// If Chi != null, the output is emitted as bf16 hi/lo planes instead of fp32.
// N-guard on the fp32 store path (used with N=176 for x_proj).
__global__ __launch_bounds__(256, 2) void gemm_mfma(
    const ushort_t* __restrict__ Ah, const ushort_t* __restrict__ Al,
    const ushort_t* __restrict__ Wh, const ushort_t* __restrict__ Wl,
    float* __restrict__ C, int N, int K, int ldA, int ldW,
    ushort_t* __restrict__ Chi, ushort_t* __restrict__ Clo)
{
    __shared__ ushort_t lds[4][128 * 32];
    const int tid  = threadIdx.x;
    const int wave = tid >> 6, lane = tid & 63;
    const int bm0 = blockIdx.y * 128, bn0 = blockIdx.x * 128;
    const int wm = (wave >> 1) * 64, wn = (wave & 1) * 64;

    const ushort_t* gp = (wave == 0) ? Ah : (wave == 1) ? Al : (wave == 2) ? Wh : Wl;
    const int ldg = (wave < 2) ? ldA : ldW;
    const int rb = (wave < 2) ? bm0 : bn0;
    const int srow = lane >> 2;           // 0..15
    const int skq  = (lane & 3) * 8;      // k offset in elements

    f32x4 acc[4][4];
#pragma unroll
    for (int i = 0; i < 4; i++)
#pragma unroll
        for (int j = 0; j < 4; j++) acc[i][j] = (f32x4){0.f, 0.f, 0.f, 0.f};

    const int lm  = lane & 15;
    const int kg8 = (lane >> 4) * 8;

    for (int k0 = 0; k0 < K; k0 += 32) {
#pragma unroll
        for (int j = 0; j < 8; j++) {
            const ushort_t* ga = gp + (size_t)(rb + j * 16 + srow) * ldg + k0 + skq;
            __builtin_amdgcn_global_load_lds(
                (const GAS unsigned*)ga, (LAS unsigned*)&lds[wave][j * 512], 16, 0, 0);
        }
        __syncthreads();

        bf16x8 ah[4], al[4], bh[4], bl[4];
#pragma unroll
        for (int i = 0; i < 4; i++) {
            const int ar = (wm + i * 16 + lm) * 32 + kg8;
            ah[i] = *(const bf16x8*)&lds[0][ar];
            al[i] = *(const bf16x8*)&lds[1][ar];
            const int br = (wn + i * 16 + lm) * 32 + kg8;
            bh[i] = *(const bf16x8*)&lds[2][br];
            bl[i] = *(const bf16x8*)&lds[3][br];
        }
#pragma unroll
        for (int mi = 0; mi < 4; mi++)
#pragma unroll
            for (int ni = 0; ni < 4; ni++) {
                f32x4 t = acc[mi][ni];
                t = __builtin_amdgcn_mfma_f32_16x16x32_bf16(al[mi], bh[ni], t, 0, 0, 0);
                t = __builtin_amdgcn_mfma_f32_16x16x32_bf16(ah[mi], bl[ni], t, 0, 0, 0);
                t = __builtin_amdgcn_mfma_f32_16x16x32_bf16(ah[mi], bh[ni], t, 0, 0, 0);
                acc[mi][ni] = t;
            }
        __syncthreads();
    }

#pragma unroll
    for (int mi = 0; mi < 4; mi++)
#pragma unroll
        for (int ni = 0; ni < 4; ni++)
#pragma unroll
            for (int r = 0; r < 4; r++) {
                const int rowg = bm0 + wm + mi * 16 + (lane >> 4) * 4 + r;
                const int colg = bn0 + wn + ni * 16 + lm;
                const float v = acc[mi][ni][r];
                if (Chi) {
                    ushort_t h, l;
                    bf16_split(v, h, l);
                    Chi[(size_t)rowg * N + colg] = h;
                    Clo[(size_t)rowg * N + colg] = l;
                } else if (colg < N) {
                    C[(size_t)rowg * N + colg] = v;
                }
            }
}

// dt GEMM, transposed output: dtT[(b*DI+d)*SEQ + t] =
//   softplus(sum_k Wdt[d][k] * xdbl[b*SEQ+t][k] + bias[d]).
__global__ __launch_bounds__(256, 2) void gemm_dt_T(
    const float* __restrict__ Wdt, const float* __restrict__ xdbl,
    const float* __restrict__ bias, float* __restrict__ dtT)
{
    __shared__ float As[8][132];
    __shared__ float Bs[8][132];
    const int tid = threadIdx.x;
    const int bd0 = blockIdx.y * 128;   // d tile
    const int bt0 = blockIdx.x * 128;   // t tile
    const int b   = blockIdx.z;
    const int tx = tid & 15;            // t group
    const int ty = tid >> 4;            // d group
    const int lrow = tid >> 1;
    const int lk4  = (tid & 1) * 4;

    float acc[8][8];
#pragma unroll
    for (int i = 0; i < 8; i++)
#pragma unroll
        for (int j = 0; j < 8; j++) acc[i][j] = 0.f;

    for (int k0 = 0; k0 < DTR; k0 += 8) {
        const float4 av = *(const float4*)(Wdt + (size_t)(bd0 + lrow) * DTR + k0 + lk4);
        const float4 wv = *(const float4*)(xdbl + ((size_t)b * SEQ + bt0 + lrow) * XDC + k0 + lk4);
        __syncthreads();
        As[lk4 + 0][lrow] = av.x; As[lk4 + 1][lrow] = av.y;
        As[lk4 + 2][lrow] = av.z; As[lk4 + 3][lrow] = av.w;
        Bs[lk4 + 0][lrow] = wv.x; Bs[lk4 + 1][lrow] = wv.y;
        Bs[lk4 + 2][lrow] = wv.z; Bs[lk4 + 3][lrow] = wv.w;
        __syncthreads();
#pragma unroll
        for (int kk = 0; kk < 8; kk++) {
            const float4 a0 = *(const float4*)&As[kk][ty * 8];
            const float4 a1 = *(const float4*)&As[kk][ty * 8 + 4];
            const float4 b0 = *(const float4*)&Bs[kk][tx * 8];
            const float4 b1 = *(const float4*)&Bs[kk][tx * 8 + 4];
            const float ar[8] = {a0.x, a0.y, a0.z, a0.w, a1.x, a1.y, a1.z, a1.w};
            const float br[8] = {b0.x, b0.y, b0.z, b0.w, b1.x, b1.y, b1.z, b1.w};
#pragma unroll
            for (int i = 0; i < 8; i++)
#pragma unroll
                for (int j = 0; j < 8; j++)
                    acc[i][j] = fmaf(ar[i], br[j], acc[i][j]);
        }
    }

#pragma unroll
    for (int i = 0; i < 8; i++) {
        const int d = bd0 + ty * 8 + i;
        const float bb = bias[d];
#pragma unroll
        for (int j4 = 0; j4 < 8; j4 += 4) {
            float4 v = make_float4(acc[i][j4], acc[i][j4 + 1], acc[i][j4 + 2], acc[i][j4 + 3]);
            v.x = softplus_acc(v.x + bb);
            v.y = softplus_acc(v.y + bb);
            v.z = softplus_acc(v.z + bb);
            v.w = softplus_acc(v.w + bb);
            *(float4*)(dtT + ((size_t)b * DI + d) * SEQ + bt0 + tx * 8 + j4) = v;
        }
    }
}

// Depthwise causal conv (K=4) + SiLU -> uT [b][d][t] fp32 AND row-major
// bf16 hi/lo planes (for the x_proj MFMA GEMM).
__global__ __launch_bounds__(256) void conv_silu_T2(
    const float* __restrict__ xz, const float* __restrict__ cw,
    const float* __restrict__ cb, float* __restrict__ uT,
    ushort_t* __restrict__ uh, ushort_t* __restrict__ ul)
{
    __shared__ float tin[67][65];
    __shared__ float ttr[64][65];
    const int tid = threadIdx.x;
    const int d0 = blockIdx.x * 64, t0 = blockIdx.y * 64, b = blockIdx.z;
    const int cl = tid & 63, q = tid >> 6;

    for (int r = q; r < 67; r += 4) {
        const int t = t0 - 3 + r;
        float v = 0.f;
        if (t >= 0) v = xz[((size_t)b * SEQ + t) * (2 * DI) + d0 + cl];
        tin[r][cl] = v;
    }
    __syncthreads();

    const float4 w = ((const float4*)cw)[d0 + cl];
    const float bb = cb[d0 + cl];
#pragma unroll
    for (int i = 0; i < 16; i++) {
        const int t = q * 16 + i;
        float a = bb;
        a = fmaf(tin[t + 0][cl], w.x, a);
        a = fmaf(tin[t + 1][cl], w.y, a);
        a = fmaf(tin[t + 2][cl], w.z, a);
        a = fmaf(tin[t + 3][cl], w.w, a);
        a = silu_fast(a);
        ttr[cl][t] = a;
        ushort_t h, l;
        bf16_split(a, h, l);
        const size_t row = (size_t)b * SEQ + t0 + t;
        uh[row * DI + d0 + cl] = h;          // coalesced in d
        ul[row * DI + d0 + cl] = l;
    }
    __syncthreads();
#pragma unroll
    for (int i = 0; i < 16; i++) {
        const int d = q * 16 + i;
        uT[((size_t)b * DI + d0 + d) * SEQ + t0 + cl] = ttr[d][cl];  // coalesced in t
    }
}

// B/C transpose into state-quad interleaved layout:
//   bcq[((b*SEQ + t)*32 + grp*16 + s] = float4{ X[t][s], X[t][s+16], X[t][s+32], X[t][s+48] }
// where X = B half (grp=0, cols DTR..DTR+63) or C half (grp=1).
// Lane (ch,s) of the quad-packed scan reads one float4 = its 4 states.
__global__ __launch_bounds__(256) void trans_bc_q(
    const float* __restrict__ in, float4* __restrict__ bcq)
{
    __shared__ float tile[64][67];
    const int tid = threadIdx.x;
    const int grp = blockIdx.x, t0 = blockIdx.y * 64, b = blockIdx.z;
    const int cl = tid & 63, q = tid >> 6;
#pragma unroll
    for (int i = 0; i < 16; i++) {
        const int r = q * 16 + i;
        tile[r][cl] = in[((size_t)b * SEQ + t0 + r) * XDC + DTR + grp * 64 + cl];
    }
    __syncthreads();
    const int s  = tid & 15;
    const int tq = tid >> 4;            // 0..15
#pragma unroll
    for (int i = 0; i < 4; i++) {
        const int t = i * 16 + tq;      // 0..63
        bcq[((size_t)b * SEQ + t0 + t) * 32 + grp * 16 + s] =
            make_float4(tile[t][s], tile[t][s + 16], tile[t][s + 32], tile[t][s + 48]);
    }
}

// ---------------- Chunked selective scan ----------------
// s output lives in the dead xz x-half via the linear map
//   addr(L) = (L/1536)*3072 + L%1536,  L = bd*SEQ + t.

// Truncated-backward chunk-end state:
//   hend = sum_t exp2(An * R_t) * dt_t*u_t*B_t,   R_t = suffix-sum of dt.
// All An < 0 and the weights decay monotonically, so once every lane's
// weight underflows 2^-30 the remaining (earlier) terms are numerically
// irrelevant.  Typical stop: ~32 of 256 steps; worst case = full chunk.
// B read from the quad-interleaved bcq layout (scalar per-t loads, the
// 64 lanes' offsets permute one 256B block -> fully coalesced).
__global__ __launch_bounds__(256, 2) void scan_tail(
    const float* __restrict__ dtT, const float* __restrict__ uT,
    const float4* __restrict__ bcq, const float* __restrict__ A_log,
    float* __restrict__ hend)
{
    const int wid  = __builtin_amdgcn_readfirstlane(
                        (int)((blockIdx.x * 256 + threadIdx.x) >> 6));
    const int lane = threadIdx.x & 63;
    const int c  = wid & (NC - 1);
    const int bd = wid >> 3;
    const int b  = bd / DI;
    const int d  = bd - b * DI;

    const float An = -expf(A_log[d * DS + lane]) * LOG2E;
    const float* dtp = dtT + (size_t)bd * SEQ + c * TCH;
    const float* up  = uT  + (size_t)bd * SEQ + c * TCH;
    // scalar B stream: B[t] = Bf[t*128]
    const float* Bf = (const float*)bcq + ((size_t)b * SEQ + c * TCH) * 128
                      + (lane & 15) * 4 + (lane >> 4);

    float h = 0.f, r = 0.f;
    for (int tb = TCH - 16; tb >= 0; tb -= 16) {
        float4 dt4[4], u4[4];
        float Bs[16];
#pragma unroll
        for (int g = 0; g < 4; g++) {
            dt4[g] = *(const float4*)(dtp + tb + 4 * g);
            u4[g]  = *(const float4*)(up  + tb + 4 * g);
        }
#pragma unroll
        for (int e = 0; e < 16; e++) Bs[e] = Bf[(size_t)(tb + e) * 128];
#pragma unroll
        for (int g = 3; g >= 0; g--) {
            h = fmaf(__builtin_amdgcn_exp2f(An * r), (dt4[g].w * u4[g].w) * Bs[4*g+3], h); r += dt4[g].w;
            h = fmaf(__builtin_amdgcn_exp2f(An * r), (dt4[g].z * u4[g].z) * Bs[4*g+2], h); r += dt4[g].z;
            h = fmaf(__builtin_amdgcn_exp2f(An * r), (dt4[g].y * u4[g].y) * Bs[4*g+1], h); r += dt4[g].y;
            h = fmaf(__builtin_amdgcn_exp2f(An * r), (dt4[g].x * u4[g].x) * Bs[4*g+0], h); r += dt4[g].x;
        }
        if (__all(An * r < -30.f)) break;   // all remaining weights < 2^-30
    }
    hend[(size_t)wid * DS + lane] = h;
}

// Cross-chunk combine (computes per-chunk dt sums internally).
__global__ __launch_bounds__(256) void scan_phase2(
    const float* __restrict__ dtT, const float* __restrict__ A_log,
    const float* __restrict__ hend, float* __restrict__ h0out)
{
    const int bd   = (blockIdx.x * 256 + threadIdx.x) >> 6;
    const int lane = threadIdx.x & 63;
    const int d    = bd % DI;

    const float* dtp = dtT + (size_t)bd * SEQ + lane * 32;
    float s = 0.f;
#pragma unroll
    for (int g = 0; g < 8; g++) {
        const float4 v = *(const float4*)(dtp + 4 * g);
        s += (v.x + v.y) + (v.z + v.w);
    }
    s += __shfl_xor(s, 1, 64);
    s += __shfl_xor(s, 2, 64);
    s += __shfl_xor(s, 4, 64);   // lanes 8c..8c+7 all hold chunk-c sum

    const float An = -expf(A_log[d * DS + lane]) * LOG2E;
    float h = 0.f;
#pragma unroll
    for (int c = 0; c < NC; c++) {
        const float sdt = __shfl(s, 8 * c, 64);
        const size_t off = ((size_t)bd * NC + c) * DS + lane;
        h0out[off] = h;
        h = fmaf(__builtin_amdgcn_exp2f(An * sdt), h, hend[off]);
    }
}

// Quad-packed full scan: lane (ch = lane>>4, s = lane&15) carries states
// {s, s+16, s+32, s+48} of channel bd = bdq*4+ch; one wave = 4 channels
// of one chunk.  4 independent h-chains/lane (ILP), local 4-state C-dot,
// 16-partial LDS transpose (4x less cross-lane traffic, no shfl stage).
__global__ __launch_bounds__(256, 2) void scan_phase3_q(
    const float* __restrict__ dtT, const float* __restrict__ uT,
    const float4* __restrict__ bcq, const float* __restrict__ A_log,
    const float* __restrict__ hin, float* __restrict__ sX)
{
    __shared__ float red[4][1280];   // per-wave slab [16 s][4 ch][20 pad]
    const int tid  = threadIdx.x;
    const int wid  = __builtin_amdgcn_readfirstlane(
                        (int)((blockIdx.x * 256 + tid) >> 6));
    const int lane = tid & 63;
    const int c   = wid & (NC - 1);
    const int bdq = wid >> 3;                 // channel-quad index
    const int b   = bdq / (DI / 4);           // 384 quads per batch
    const int ch  = lane >> 4, s = lane & 15;
    const int bd  = bdq * 4 + ch;
    const int d   = bd - b * DI;

    float An[4], h[4];
#pragma unroll
    for (int k = 0; k < 4; k++) {
        An[k] = -expf(A_log[(size_t)d * DS + s + 16 * k]) * LOG2E;
        h[k]  = hin[((size_t)bd * NC + c) * DS + s + 16 * k];
    }

    const float*  dtp = dtT + (size_t)bd * SEQ + c * TCH;
    const float*  up  = uT  + (size_t)bd * SEQ + c * TCH;
    const float4* Bq  = bcq + ((size_t)b * SEQ + c * TCH) * 32 + s;
    const float4* Cq  = Bq + 16;

    float* slab = &red[tid >> 6][0];
    const int wrow  = (s * 4 + ch) * 20;      // writer row (words)
    const int rbase = ch * 20 + s;            // reader: (rch=ch, rtt=s)
    // store base for reader role: channel bd, t = c*TCH + tb + s
    const int Lrow = bd * SEQ + c * TCH;

    for (int tb = 0; tb < TCH; tb += 16) {
#pragma unroll
        for (int g = 0; g < 4; g++) {
            const int t0 = tb + g * 4;
            const float4 dt4 = *(const float4*)(dtp + t0);
            const float4 u4  = *(const float4*)(up  + t0);
            float4 B4[4], C4[4];
#pragma unroll
            for (int e = 0; e < 4; e++) {
                B4[e] = Bq[(size_t)(t0 + e) * 32];
                C4[e] = Cq[(size_t)(t0 + e) * 32];
            }
            float lf[4];
#pragma unroll
            for (int e = 0; e < 4; e++) {
                const float dte = ((const float*)&dt4)[e];
                const float due = dte * ((const float*)&u4)[e];
                h[0] = fmaf(__builtin_amdgcn_exp2f(dte * An[0]), h[0], due * B4[e].x);
                h[1] = fmaf(__builtin_amdgcn_exp2f(dte * An[1]), h[1], due * B4[e].y);
                h[2] = fmaf(__builtin_amdgcn_exp2f(dte * An[2]), h[2], due * B4[e].z);
                h[3] = fmaf(__builtin_amdgcn_exp2f(dte * An[3]), h[3], due * B4[e].w);
                lf[e] = (h[0] * C4[e].x + h[1] * C4[e].y)
                      + (h[2] * C4[e].z + h[3] * C4[e].w);
            }
            *(f32x4*)&slab[wrow + g * 4] = (f32x4){lf[0], lf[1], lf[2], lf[3]};
        }
        // reduce 16 s-partials for output (ch, tb + s) -- all in-lane
        float v[16];
#pragma unroll
        for (int si = 0; si < 16; si++) v[si] = slab[rbase + si * 80];
        const float y = (((v[0] + v[1]) + (v[2] + v[3]))
                       + ((v[4] + v[5]) + (v[6] + v[7])))
                      + (((v[8] + v[9]) + (v[10] + v[11]))
                       + ((v[12] + v[13]) + (v[14] + v[15])));
        const int L0 = Lrow + tb;                 // multiple of 16
        sX[(size_t)(L0 / 1536) * 3072 + (L0 % 1536) + s] = y;
    }
}

// Fused gate + transpose + bf16-split:
//   y = (s + D*u) * silu(z), emitted directly as row-major bf16 planes yh/yl.
__global__ __launch_bounds__(256) void gate_split_T(
    const float* __restrict__ xz, const float* __restrict__ uT,
    const float* __restrict__ Dskip,
    ushort_t* __restrict__ yh, ushort_t* __restrict__ yl)
{
    __shared__ float zt[64][65];   // [t][d]
    __shared__ float yt[64][65];   // [d][t]
    const int tid = threadIdx.x;
    const int d0 = blockIdx.x * 64, t0 = blockIdx.y * 64, b = blockIdx.z;
    const int cl = tid & 63, q = tid >> 6;
#pragma unroll
    for (int i = 0; i < 16; i++) {
        const int r = q * 16 + i;
        zt[r][cl] = xz[((size_t)b * SEQ + t0 + r) * (2 * DI) + DI + d0 + cl];
    }
    __syncthreads();
#pragma unroll
    for (int i = 0; i < 16; i++) {
        const int dd = q * 16 + i;
        const size_t Lrow = ((size_t)b * DI + d0 + dd) * SEQ + t0;
        const float s = xz[(Lrow / 1536) * 3072 + (Lrow % 1536) + cl];
        const float u = uT[Lrow + cl];
        const float Dd = Dskip[d0 + dd];   // wave-uniform
        yt[dd][cl] = (s + Dd * u) * silu_fast(zt[cl][dd]);
    }
    __syncthreads();
#pragma unroll
    for (int i = 0; i < 16; i++) {
        const int t = q * 16 + i;
        ushort_t h, l;
        bf16_split(yt[cl][t], h, l);
        const size_t row = (size_t)b * SEQ + t0 + t;
        yh[row * DI + d0 + cl] = h;        // coalesced in d
        yl[row * DI + d0 + cl] = l;
    }
}

extern "C" void kernel_launch(void* const* d_in, const int* in_sizes, int n_in,
                              void* d_out, int out_size, void* d_ws, size_t ws_size,
                              hipStream_t stream) {
    (void)in_sizes; (void)n_in; (void)out_size; (void)ws_size;
    const float* x    = (const float*)d_in[0];
    const float* Wi   = (const float*)d_in[1];
    const float* cw   = (const float*)d_in[2];
    const float* cb   = (const float*)d_in[3];
    const float* Wx   = (const float*)d_in[4];
    const float* Wdt  = (const float*)d_in[5];
    const float* bdt  = (const float*)d_in[6];
    const float* Alog = (const float*)d_in[7];
    const float* Dsk  = (const float*)d_in[8];
    const float* Wo   = (const float*)d_in[9];
    float* out = (float*)d_out;

    // Workspace (fp32) regions:
    float* xz    = (float*)d_ws;                          // [MROWS, 3072]
    float* uT    = xz    + (size_t)MROWS * (2 * DI);
    float* dtT   = uT    + (size_t)MROWS * DI;
    float* xdbl  = dtT   + (size_t)MROWS * DI;
    float* bcT   = xdbl  + (size_t)MROWS * XDC;
    float* xnext = bcT   + (size_t)BATCH * 128 * SEQ;
    float* hend  = xnext;                                 // [B*DI*NC, DS]
    float* h0buf = xnext + (size_t)BATCH * DI * NC * DS;  // [B*DI*NC, DS]

    // bf16 plane homes (all lifetimes disjoint on the serial stream):
    ushort_t* sh  = (ushort_t*)uT;
    ushort_t* sl  = sh  + (size_t)MROWS * DM;
    ushort_t* wih = (ushort_t*)(dtT + (size_t)MROWS * DM);
    ushort_t* wil = wih + (size_t)2 * DI * DM;
    ushort_t* uh  = (ushort_t*)dtT;
    ushort_t* ul  = uh  + (size_t)MROWS * DI;
    ushort_t* wxh = (ushort_t*)bcT;
    ushort_t* wxl = wxh + (size_t)256 * DI;
    ushort_t* woh = (ushort_t*)xdbl;
    ushort_t* wol = woh + (size_t)DM * DI;
    ushort_t* yh  = (ushort_t*)xnext;
    ushort_t* yl  = (ushort_t*)(dtT + (size_t)MROWS * DM);

    for (int i = 0; i < DEPTH; i++) {
        const float* Wi_l   = Wi   + (size_t)i * 2 * DI * DM;
        const float* cw_l   = cw   + (size_t)i * DI * DC;
        const float* cb_l   = cb   + (size_t)i * DI;
        const float* Wx_l   = Wx   + (size_t)i * XDC * DI;
        const float* Wdt_l  = Wdt  + (size_t)i * DI * DTR;
        const float* bdt_l  = bdt  + (size_t)i * DI;
        const float* Alog_l = Alog + (size_t)i * DI * DS;
        const float* Dsk_l  = Dsk  + (size_t)i * DI;
        const float* Wo_l   = Wo   + (size_t)i * DM * DI;

        // 1. input planes
        if (i == 0)
            split_bf16<<<(size_t)MROWS * DM / 1024, 256, 0, stream>>>(x, sh, sl);
        split_bf16<<<(size_t)2 * DI * DM / 1024, 256, 0, stream>>>(Wi_l, wih, wil);
        // 2. xz = src @ Wi^T
        gemm_mfma<<<dim3(2 * DI / 128, MROWS / 128), 256, 0, stream>>>(
            sh, sl, wih, wil, xz, 2 * DI, DM, DM, DM, nullptr, nullptr);
        // 3. u = silu(conv(xz[:, :DI]))
        conv_silu_T2<<<dim3(DI / 64, SEQ / 64, BATCH), 256, 0, stream>>>(
            xz, cw_l, cb_l, uT, uh, ul);
        // 4. Wx planes
        split_bf16<<<(size_t)XDC * DI / 1024, 256, 0, stream>>>(Wx_l, wxh, wxl);
        // 5. xdbl = u @ Wx^T
        gemm_mfma<<<dim3((XDC + 127) / 128, MROWS / 128), 256, 0, stream>>>(
            uh, ul, wxh, wxl, xdbl, XDC, DI, DI, DI, nullptr, nullptr);
        // 6. B/C -> state-quad interleaved bcq layout
        trans_bc_q<<<dim3(2, SEQ / 64, BATCH), 256, 0, stream>>>(
            xdbl, (float4*)bcT);
        // 7. dtT = softplus(Wdt @ xdbl_dt^T + bdt)
        gemm_dt_T<<<dim3(SEQ / 128, DI / 128, BATCH), 256, 0, stream>>>(
            Wdt_l, xdbl, bdt_l, dtT);
        // 8. truncated-backward chunk-end states
        scan_tail<<<(BATCH * DI * NC) / 4, 256, 0, stream>>>(
            dtT, uT, (const float4*)bcT, Alog_l, hend);
        // 9. cross-chunk combine
        scan_phase2<<<(BATCH * DI) / 4, 256, 0, stream>>>(
            dtT, Alog_l, hend, h0buf);
        // 10. quad-packed full scan; writes s into xz x-half (mapped)
        scan_phase3_q<<<(BATCH * DI * NC) / 16, 256, 0, stream>>>(
            dtT, uT, (const float4*)bcT, Alog_l, h0buf, xz);
        // 11. fused gate + split
        gate_split_T<<<dim3(DI / 64, SEQ / 64, BATCH), 256, 0, stream>>>(
            xz, uT, Dsk_l, yh, yl);
        // 12. Wo planes
        split_bf16<<<(size_t)DM * DI / 1024, 256, 0, stream>>>(Wo_l, woh, wol);
        // 13. out = y @ Wo^T
        if (i == DEPTH - 1)
            gemm_mfma<<<dim3(DM / 128, MROWS / 128), 256, 0, stream>>>(
                yh, yl, woh, wol, out, DM, DI, DI, DI, nullptr, nullptr);
        else
            gemm_mfma<<<dim3(DM / 128, MROWS / 128), 256, 0, stream>>>(
                yh, yl, woh, wol, xz /*unused*/, DM, DI, DI, DI, sh, sl);
    }
}

// Round 3
// 1471.322 us; speedup vs baseline: 1.1062x; 1.1062x over previous
//
#include <hip/hip_runtime.h>
#include <hip/hip_bf16.h>
#include <math.h>

// Problem constants (MambaStack reference)
#define DEPTH   2
#define DM      768      // d_model
#define DS      64       // d_state
#define DC      4        // d_conv
#define DI      1536     // d_inner
#define DTR     48       // dt_rank
#define BATCH   4
#define SEQ     2048
#define MROWS   (BATCH*SEQ)          // 8192
#define XDC     (DTR + 2*DS)         // 176 (xdbl cols)
#define NC      8                    // scan chunks
#define TCH     (SEQ/NC)             // 256 timesteps per chunk
#define LOG2E   1.44269504088896f

typedef __attribute__((ext_vector_type(8))) short bf16x8;
typedef __attribute__((ext_vector_type(4))) float f32x4;
typedef unsigned short ushort_t;
#define GAS __attribute__((address_space(1)))
#define LAS __attribute__((address_space(3)))

__device__ __forceinline__ float silu_fast(float x) {
    return x / (1.f + __expf(-x));
}
__device__ __forceinline__ float softplus_acc(float x) {
    return x > 20.f ? x : log1pf(expf(x));
}

// Split fp32 -> (hi, lo) bf16 pair, both RNE.  hi+lo represents f to ~2^-17.
__device__ __forceinline__ void bf16_split(float f, ushort_t& h, ushort_t& l) {
    unsigned u = __float_as_uint(f);
    unsigned hr = u + 0x7FFF + ((u >> 16) & 1);
    h = (ushort_t)(hr >> 16);
    float lof = f - __uint_as_float((unsigned)h << 16);
    unsigned ul = __float_as_uint(lof);
    unsigned lr = ul + 0x7FFF + ((ul >> 16) & 1);
    l = (ushort_t)(lr >> 16);
}

// Contiguous fp32 array -> hi/lo bf16 planes.  n multiple of 1024.
__global__ __launch_bounds__(256) void split_bf16(
    const float* __restrict__ in, ushort_t* __restrict__ hi,
    ushort_t* __restrict__ lo)
{
    const size_t i = ((size_t)blockIdx.x * 256 + threadIdx.x) * 4;
    const float4 v = *(const float4*)(in + i);
    ushort4 h, l;
    bf16_split(v.x, h.x, l.x); bf16_split(v.y, h.y, l.y);
    bf16_split(v.z, h.z, l.z); bf16_split(v.w, h.w, l.w);
    *(ushort4*)(hi + i) = h;
    *(ushort4*)(lo + i) = l;
}

// ---------------- bf16x2-split MFMA GEMM ----------------
// C[M,N] = (Ah+Al) @ (Wh+Wl)^T, planes bf16, row strides ldA/ldW (elements).
// 128x128 tile, BK=32, 4 waves; 16x16x32 MFMA, 3 per tile (hh, hl, lh).
// If Chi != null, the output is emitted as bf16 hi/lo planes instead of fp32.
// N-guard on the fp32 store path (used with N=176 for x_proj).
__global__ __launch_bounds__(256, 2) void gemm_mfma(
    const ushort_t* __restrict__ Ah, const ushort_t* __restrict__ Al,
    const ushort_t* __restrict__ Wh, const ushort_t* __restrict__ Wl,
    float* __restrict__ C, int N, int K, int ldA, int ldW,
    ushort_t* __restrict__ Chi, ushort_t* __restrict__ Clo)
{
    __shared__ ushort_t lds[4][128 * 32];
    const int tid  = threadIdx.x;
    const int wave = tid >> 6, lane = tid & 63;
    const int bm0 = blockIdx.y * 128, bn0 = blockIdx.x * 128;
    const int wm = (wave >> 1) * 64, wn = (wave & 1) * 64;

    const ushort_t* gp = (wave == 0) ? Ah : (wave == 1) ? Al : (wave == 2) ? Wh : Wl;
    const int ldg = (wave < 2) ? ldA : ldW;
    const int rb = (wave < 2) ? bm0 : bn0;
    const int srow = lane >> 2;           // 0..15
    const int skq  = (lane & 3) * 8;      // k offset in elements

    f32x4 acc[4][4];
#pragma unroll
    for (int i = 0; i < 4; i++)
#pragma unroll
        for (int j = 0; j < 4; j++) acc[i][j] = (f32x4){0.f, 0.f, 0.f, 0.f};

    const int lm  = lane & 15;
    const int kg8 = (lane >> 4) * 8;

    for (int k0 = 0; k0 < K; k0 += 32) {
#pragma unroll
        for (int j = 0; j < 8; j++) {
            const ushort_t* ga = gp + (size_t)(rb + j * 16 + srow) * ldg + k0 + skq;
            __builtin_amdgcn_global_load_lds(
                (const GAS unsigned*)ga, (LAS unsigned*)&lds[wave][j * 512], 16, 0, 0);
        }
        __syncthreads();

        bf16x8 ah[4], al[4], bh[4], bl[4];
#pragma unroll
        for (int i = 0; i < 4; i++) {
            const int ar = (wm + i * 16 + lm) * 32 + kg8;
            ah[i] = *(const bf16x8*)&lds[0][ar];
            al[i] = *(const bf16x8*)&lds[1][ar];
            const int br = (wn + i * 16 + lm) * 32 + kg8;
            bh[i] = *(const bf16x8*)&lds[2][br];
            bl[i] = *(const bf16x8*)&lds[3][br];
        }
#pragma unroll
        for (int mi = 0; mi < 4; mi++)
#pragma unroll
            for (int ni = 0; ni < 4; ni++) {
                f32x4 t = acc[mi][ni];
                t = __builtin_amdgcn_mfma_f32_16x16x32_bf16(al[mi], bh[ni], t, 0, 0, 0);
                t = __builtin_amdgcn_mfma_f32_16x16x32_bf16(ah[mi], bl[ni], t, 0, 0, 0);
                t = __builtin_amdgcn_mfma_f32_16x16x32_bf16(ah[mi], bh[ni], t, 0, 0, 0);
                acc[mi][ni] = t;
            }
        __syncthreads();
    }

#pragma unroll
    for (int mi = 0; mi < 4; mi++)
#pragma unroll
        for (int ni = 0; ni < 4; ni++)
#pragma unroll
            for (int r = 0; r < 4; r++) {
                const int rowg = bm0 + wm + mi * 16 + (lane >> 4) * 4 + r;
                const int colg = bn0 + wn + ni * 16 + lm;
                const float v = acc[mi][ni][r];
                if (Chi) {
                    ushort_t h, l;
                    bf16_split(v, h, l);
                    Chi[(size_t)rowg * N + colg] = h;
                    Clo[(size_t)rowg * N + colg] = l;
                } else if (colg < N) {
                    C[(size_t)rowg * N + colg] = v;
                }
            }
}

// dt GEMM, transposed output: dtT[(b*DI+d)*SEQ + t] =
//   softplus(sum_k Wdt[d][k] * xdbl[b*SEQ+t][k] + bias[d]).
__global__ __launch_bounds__(256, 2) void gemm_dt_T(
    const float* __restrict__ Wdt, const float* __restrict__ xdbl,
    const float* __restrict__ bias, float* __restrict__ dtT)
{
    __shared__ float As[8][132];
    __shared__ float Bs[8][132];
    const int tid = threadIdx.x;
    const int bd0 = blockIdx.y * 128;   // d tile
    const int bt0 = blockIdx.x * 128;   // t tile
    const int b   = blockIdx.z;
    const int tx = tid & 15;            // t group
    const int ty = tid >> 4;            // d group
    const int lrow = tid >> 1;
    const int lk4  = (tid & 1) * 4;

    float acc[8][8];
#pragma unroll
    for (int i = 0; i < 8; i++)
#pragma unroll
        for (int j = 0; j < 8; j++) acc[i][j] = 0.f;

    for (int k0 = 0; k0 < DTR; k0 += 8) {
        const float4 av = *(const float4*)(Wdt + (size_t)(bd0 + lrow) * DTR + k0 + lk4);
        const float4 wv = *(const float4*)(xdbl + ((size_t)b * SEQ + bt0 + lrow) * XDC + k0 + lk4);
        __syncthreads();
        As[lk4 + 0][lrow] = av.x; As[lk4 + 1][lrow] = av.y;
        As[lk4 + 2][lrow] = av.z; As[lk4 + 3][lrow] = av.w;
        Bs[lk4 + 0][lrow] = wv.x; Bs[lk4 + 1][lrow] = wv.y;
        Bs[lk4 + 2][lrow] = wv.z; Bs[lk4 + 3][lrow] = wv.w;
        __syncthreads();
#pragma unroll
        for (int kk = 0; kk < 8; kk++) {
            const float4 a0 = *(const float4*)&As[kk][ty * 8];
            const float4 a1 = *(const float4*)&As[kk][ty * 8 + 4];
            const float4 b0 = *(const float4*)&Bs[kk][tx * 8];
            const float4 b1 = *(const float4*)&Bs[kk][tx * 8 + 4];
            const float ar[8] = {a0.x, a0.y, a0.z, a0.w, a1.x, a1.y, a1.z, a1.w};
            const float br[8] = {b0.x, b0.y, b0.z, b0.w, b1.x, b1.y, b1.z, b1.w};
#pragma unroll
            for (int i = 0; i < 8; i++)
#pragma unroll
                for (int j = 0; j < 8; j++)
                    acc[i][j] = fmaf(ar[i], br[j], acc[i][j]);
        }
    }

#pragma unroll
    for (int i = 0; i < 8; i++) {
        const int d = bd0 + ty * 8 + i;
        const float bb = bias[d];
#pragma unroll
        for (int j4 = 0; j4 < 8; j4 += 4) {
            float4 v = make_float4(acc[i][j4], acc[i][j4 + 1], acc[i][j4 + 2], acc[i][j4 + 3]);
            v.x = softplus_acc(v.x + bb);
            v.y = softplus_acc(v.y + bb);
            v.z = softplus_acc(v.z + bb);
            v.w = softplus_acc(v.w + bb);
            *(float4*)(dtT + ((size_t)b * DI + d) * SEQ + bt0 + tx * 8 + j4) = v;
        }
    }
}

// Depthwise causal conv (K=4) + SiLU -> uT [b][d][t] fp32 AND row-major
// bf16 hi/lo planes (for the x_proj MFMA GEMM).
__global__ __launch_bounds__(256) void conv_silu_T2(
    const float* __restrict__ xz, const float* __restrict__ cw,
    const float* __restrict__ cb, float* __restrict__ uT,
    ushort_t* __restrict__ uh, ushort_t* __restrict__ ul)
{
    __shared__ float tin[67][65];
    __shared__ float ttr[64][65];
    const int tid = threadIdx.x;
    const int d0 = blockIdx.x * 64, t0 = blockIdx.y * 64, b = blockIdx.z;
    const int cl = tid & 63, q = tid >> 6;

    for (int r = q; r < 67; r += 4) {
        const int t = t0 - 3 + r;
        float v = 0.f;
        if (t >= 0) v = xz[((size_t)b * SEQ + t) * (2 * DI) + d0 + cl];
        tin[r][cl] = v;
    }
    __syncthreads();

    const float4 w = ((const float4*)cw)[d0 + cl];
    const float bb = cb[d0 + cl];
#pragma unroll
    for (int i = 0; i < 16; i++) {
        const int t = q * 16 + i;
        float a = bb;
        a = fmaf(tin[t + 0][cl], w.x, a);
        a = fmaf(tin[t + 1][cl], w.y, a);
        a = fmaf(tin[t + 2][cl], w.z, a);
        a = fmaf(tin[t + 3][cl], w.w, a);
        a = silu_fast(a);
        ttr[cl][t] = a;
        ushort_t h, l;
        bf16_split(a, h, l);
        const size_t row = (size_t)b * SEQ + t0 + t;
        uh[row * DI + d0 + cl] = h;          // coalesced in d
        ul[row * DI + d0 + cl] = l;
    }
    __syncthreads();
#pragma unroll
    for (int i = 0; i < 16; i++) {
        const int d = q * 16 + i;
        uT[((size_t)b * DI + d0 + d) * SEQ + t0 + cl] = ttr[d][cl];  // coalesced in t
    }
}

// B/C transpose into lane-interleaved layout:
//   bc4[(b*(SEQ/4) + t/4)*128 + ch] = float4{ x[t..t+3][ch] }
__global__ __launch_bounds__(256) void trans_bc_i4(
    const float* __restrict__ in, float4* __restrict__ bc4)
{
    __shared__ float tile[64][65];
    const int tid = threadIdx.x;
    const int c0 = blockIdx.x * 64, t0 = blockIdx.y * 64, b = blockIdx.z;
    const int cl = tid & 63, q = tid >> 6;
#pragma unroll
    for (int i = 0; i < 16; i++) {
        const int r = q * 16 + i;
        tile[r][cl] = in[((size_t)b * SEQ + t0 + r) * XDC + DTR + c0 + cl];
    }
    __syncthreads();
#pragma unroll
    for (int i = 0; i < 4; i++) {
        const int j = q * 4 + i;
        const float4 v = make_float4(tile[4 * j + 0][cl], tile[4 * j + 1][cl],
                                     tile[4 * j + 2][cl], tile[4 * j + 3][cl]);
        bc4[((size_t)b * (SEQ / 4) + (t0 / 4 + j)) * 128 + c0 + cl] = v;
    }
}

// ---------------- Chunked selective scan ----------------
// s output lives in the dead xz x-half via the linear map
//   addr(L) = (L/1536)*3072 + L%1536,  L = bd*SEQ + t.
// (chunks never straddle a 1536 boundary: L0 % 1536 is a multiple of 256
//  and TCH = 256, so each chunk's 256 outputs are contiguous.)

// Truncated-backward chunk-end state:
//   hend = sum_t exp2(An * R_t) * dt_t*u_t*B_t,   R_t = suffix-sum of dt.
// All An < 0 and the weights decay monotonically, so once every lane's
// weight underflows 2^-30 the remaining (earlier) terms are numerically
// irrelevant.  Typical stop: ~32 of 256 steps; worst case = full chunk.
__global__ __launch_bounds__(256, 2) void scan_tail(
    const float* __restrict__ dtT, const float* __restrict__ uT,
    const float4* __restrict__ bc4, const float* __restrict__ A_log,
    float* __restrict__ hend)
{
    const int wid  = __builtin_amdgcn_readfirstlane(
                        (int)((blockIdx.x * 256 + threadIdx.x) >> 6));
    const int lane = threadIdx.x & 63;
    const int c  = wid & (NC - 1);
    const int bd = wid >> 3;
    const int b  = bd / DI;
    const int d  = bd - b * DI;

    const float An = -expf(A_log[d * DS + lane]) * LOG2E;
    const float* dtp = dtT + (size_t)bd * SEQ + c * TCH;
    const float* up  = uT  + (size_t)bd * SEQ + c * TCH;
    const float4* Bp = bc4 + ((size_t)b * (SEQ / 4) + c * (TCH / 4)) * 128 + lane;

    float h = 0.f, r = 0.f;
    for (int tb = TCH - 16; tb >= 0; tb -= 16) {
        float4 dt4[4], u4[4], B4[4];
#pragma unroll
        for (int g = 0; g < 4; g++) {
            dt4[g] = *(const float4*)(dtp + tb + 4 * g);
            u4[g]  = *(const float4*)(up  + tb + 4 * g);
            B4[g]  = Bp[(size_t)(tb / 4 + g) * 128];
        }
#pragma unroll
        for (int g = 3; g >= 0; g--) {
            h = fmaf(__builtin_amdgcn_exp2f(An * r), (dt4[g].w * u4[g].w) * B4[g].w, h); r += dt4[g].w;
            h = fmaf(__builtin_amdgcn_exp2f(An * r), (dt4[g].z * u4[g].z) * B4[g].z, h); r += dt4[g].z;
            h = fmaf(__builtin_amdgcn_exp2f(An * r), (dt4[g].y * u4[g].y) * B4[g].y, h); r += dt4[g].y;
            h = fmaf(__builtin_amdgcn_exp2f(An * r), (dt4[g].x * u4[g].x) * B4[g].x, h); r += dt4[g].x;
        }
        if (__all(An * r < -30.f)) break;   // all remaining weights < 2^-30
    }
    hend[(size_t)wid * DS + lane] = h;
}

// Cross-chunk combine (computes per-chunk dt sums internally).
__global__ __launch_bounds__(256) void scan_phase2(
    const float* __restrict__ dtT, const float* __restrict__ A_log,
    const float* __restrict__ hend, float* __restrict__ h0out)
{
    const int bd   = (blockIdx.x * 256 + threadIdx.x) >> 6;
    const int lane = threadIdx.x & 63;
    const int d    = bd % DI;

    const float* dtp = dtT + (size_t)bd * SEQ + lane * 32;
    float s = 0.f;
#pragma unroll
    for (int g = 0; g < 8; g++) {
        const float4 v = *(const float4*)(dtp + 4 * g);
        s += (v.x + v.y) + (v.z + v.w);
    }
    s += __shfl_xor(s, 1, 64);
    s += __shfl_xor(s, 2, 64);
    s += __shfl_xor(s, 4, 64);   // lanes 8c..8c+7 all hold chunk-c sum

    const float An = -expf(A_log[d * DS + lane]) * LOG2E;
    float h = 0.f;
#pragma unroll
    for (int c = 0; c < NC; c++) {
        const float sdt = __shfl(s, 8 * c, 64);
        const size_t off = ((size_t)bd * NC + c) * DS + lane;
        h0out[off] = h;
        h = fmaf(__builtin_amdgcn_exp2f(An * sdt), h, hend[off]);
    }
}

// Dual-chunk full scan: wave handles chunks (2cp, 2cp+1) of one channel,
// interleaved at 16-t block granularity.  This places ~a full compute
// block between each load pack and its use AND between each slab write
// and its reduce read (r1 read the slab immediately after writing it).
// Reduce reads are ds_read_b128 (slab row stride 68 words, 16B-aligned).

#define SC_LOADS(DT, UU, BB_, CC_, dtp, up, Bp, Cp, TB)                \
    _Pragma("unroll")                                                  \
    for (int g = 0; g < 4; g++) {                                      \
        DT[g]  = *(const float4*)((dtp) + (TB) + 4 * g);               \
        UU[g]  = *(const float4*)((up) + (TB) + 4 * g);                \
        BB_[g] = (Bp)[(size_t)((TB) / 4 + g) * 128];                   \
        CC_[g] = (Cp)[(size_t)((TB) / 4 + g) * 128];                   \
    }

#define SC_CBLOCK(DT, UU, BB_, CC_, H, SLAB)                                                       \
    {                                                                                              \
        float p[16];                                                                               \
        _Pragma("unroll")                                                                          \
        for (int g = 0; g < 4; g++) {                                                              \
            H = fmaf(__builtin_amdgcn_exp2f(DT[g].x * An), H, (DT[g].x * UU[g].x) * BB_[g].x); p[4*g+0] = H * CC_[g].x; \
            H = fmaf(__builtin_amdgcn_exp2f(DT[g].y * An), H, (DT[g].y * UU[g].y) * BB_[g].y); p[4*g+1] = H * CC_[g].y; \
            H = fmaf(__builtin_amdgcn_exp2f(DT[g].z * An), H, (DT[g].z * UU[g].z) * BB_[g].z); p[4*g+2] = H * CC_[g].z; \
            H = fmaf(__builtin_amdgcn_exp2f(DT[g].w * An), H, (DT[g].w * UU[g].w) * BB_[g].w); p[4*g+3] = H * CC_[g].w; \
        }                                                                                          \
        _Pragma("unroll")                                                                          \
        for (int i = 0; i < 16; i++) (SLAB)[i * 68 + lane] = p[i];                                 \
    }

#define SC_RBLOCK(SLAB, SP, TBASE)                                                                 \
    {                                                                                              \
        const float* rp = (SLAB) + tt * 68 + seg * 16;                                             \
        const f32x4 r0 = *(const f32x4*)(rp);                                                      \
        const f32x4 r1 = *(const f32x4*)(rp + 4);                                                  \
        const f32x4 r2 = *(const f32x4*)(rp + 8);                                                  \
        const f32x4 r3 = *(const f32x4*)(rp + 12);                                                 \
        float s = (((r0[0] + r0[1]) + (r0[2] + r0[3])) + ((r1[0] + r1[1]) + (r1[2] + r1[3])))      \
                + (((r2[0] + r2[1]) + (r2[2] + r2[3])) + ((r3[0] + r3[1]) + (r3[2] + r3[3])));     \
        s += __shfl_xor(s, 16, 64);                                                                \
        s += __shfl_xor(s, 32, 64);                                                                \
        if (lane < 16) (SP)[(TBASE) + tt] = s;                                                     \
    }

__global__ __launch_bounds__(256, 2) void scan_phase3_d(
    const float* __restrict__ dtT, const float* __restrict__ uT,
    const float4* __restrict__ bc4, const float* __restrict__ A_log,
    const float* __restrict__ hin, float* __restrict__ sX)
{
    __shared__ __align__(16) float red[4][2][16 * 68];
    const int tid  = threadIdx.x;
    const int wid  = __builtin_amdgcn_readfirstlane(
                        (int)((blockIdx.x * 256 + tid) >> 6));
    const int lane = tid & 63;
    const int cp = wid & (NC / 2 - 1);
    const int bd = wid >> 2;
    const int b  = bd / DI;
    const int d  = bd - b * DI;
    const int c0 = cp * 2;

    const float An = -expf(A_log[d * DS + lane]) * LOG2E;
    const float* dtp0 = dtT + (size_t)bd * SEQ + c0 * TCH;
    const float* up0  = uT  + (size_t)bd * SEQ + c0 * TCH;
    const float* dtp1 = dtp0 + TCH;
    const float* up1  = up0  + TCH;
    const float4* Bp0 = bc4 + ((size_t)b * (SEQ / 4) + c0 * (TCH / 4)) * 128 + lane;
    const float4* Cp0 = Bp0 + 64;
    const float4* Bp1 = Bp0 + (TCH / 4) * 128;
    const float4* Cp1 = Cp0 + (TCH / 4) * 128;

    const size_t L00 = (size_t)bd * SEQ + (size_t)c0 * TCH;
    const size_t L01 = L00 + TCH;
    float* sp0 = sX + (L00 / 1536) * 3072 + (L00 % 1536);
    float* sp1 = sX + (L01 / 1536) * 3072 + (L01 % 1536);

    float* slab0 = &red[tid >> 6][0][0];
    float* slab1 = &red[tid >> 6][1][0];
    const int tt = lane & 15, seg = lane >> 4;

    float4 dA[4], uA[4], BA[4], CA[4], dB[4], uB[4], BB_[4], CB[4];
    float h0 = hin[((size_t)bd * NC + c0) * DS + lane];
    float h1 = hin[((size_t)bd * NC + c0 + 1) * DS + lane];

    SC_LOADS(dA, uA, BA, CA, dtp0, up0, Bp0, Cp0, 0);
    for (int tb = 0; tb < TCH; tb += 16) {
        SC_LOADS(dB, uB, BB_, CB, dtp1, up1, Bp1, Cp1, tb);
        SC_CBLOCK(dA, uA, BA, CA, h0, slab0);
        if (tb) SC_RBLOCK(slab1, sp1, tb - 16);
        SC_LOADS(dA, uA, BA, CA, dtp0, up0, Bp0, Cp0, tb + 16);  // final iter overreads into c1 (safe)
        SC_CBLOCK(dB, uB, BB_, CB, h1, slab1);
        SC_RBLOCK(slab0, sp0, tb);
    }
    SC_RBLOCK(slab1, sp1, TCH - 16);
}

// Fused gate + transpose + bf16-split:
//   y = (s + D*u) * silu(z), emitted directly as row-major bf16 planes yh/yl.
__global__ __launch_bounds__(256) void gate_split_T(
    const float* __restrict__ xz, const float* __restrict__ uT,
    const float* __restrict__ Dskip,
    ushort_t* __restrict__ yh, ushort_t* __restrict__ yl)
{
    __shared__ float zt[64][65];   // [t][d]
    __shared__ float yt[64][65];   // [d][t]
    const int tid = threadIdx.x;
    const int d0 = blockIdx.x * 64, t0 = blockIdx.y * 64, b = blockIdx.z;
    const int cl = tid & 63, q = tid >> 6;
#pragma unroll
    for (int i = 0; i < 16; i++) {
        const int r = q * 16 + i;
        zt[r][cl] = xz[((size_t)b * SEQ + t0 + r) * (2 * DI) + DI + d0 + cl];
    }
    __syncthreads();
#pragma unroll
    for (int i = 0; i < 16; i++) {
        const int dd = q * 16 + i;
        const size_t Lrow = ((size_t)b * DI + d0 + dd) * SEQ + t0;
        const float s = xz[(Lrow / 1536) * 3072 + (Lrow % 1536) + cl];
        const float u = uT[Lrow + cl];
        const float Dd = Dskip[d0 + dd];   // wave-uniform
        yt[dd][cl] = (s + Dd * u) * silu_fast(zt[cl][dd]);
    }
    __syncthreads();
#pragma unroll
    for (int i = 0; i < 16; i++) {
        const int t = q * 16 + i;
        ushort_t h, l;
        bf16_split(yt[cl][t], h, l);
        const size_t row = (size_t)b * SEQ + t0 + t;
        yh[row * DI + d0 + cl] = h;        // coalesced in d
        yl[row * DI + d0 + cl] = l;
    }
}

extern "C" void kernel_launch(void* const* d_in, const int* in_sizes, int n_in,
                              void* d_out, int out_size, void* d_ws, size_t ws_size,
                              hipStream_t stream) {
    (void)in_sizes; (void)n_in; (void)out_size; (void)ws_size;
    const float* x    = (const float*)d_in[0];
    const float* Wi   = (const float*)d_in[1];
    const float* cw   = (const float*)d_in[2];
    const float* cb   = (const float*)d_in[3];
    const float* Wx   = (const float*)d_in[4];
    const float* Wdt  = (const float*)d_in[5];
    const float* bdt  = (const float*)d_in[6];
    const float* Alog = (const float*)d_in[7];
    const float* Dsk  = (const float*)d_in[8];
    const float* Wo   = (const float*)d_in[9];
    float* out = (float*)d_out;

    // Workspace (fp32) regions:
    float* xz    = (float*)d_ws;                          // [MROWS, 3072]
    float* uT    = xz    + (size_t)MROWS * (2 * DI);
    float* dtT   = uT    + (size_t)MROWS * DI;
    float* xdbl  = dtT   + (size_t)MROWS * DI;
    float* bcT   = xdbl  + (size_t)MROWS * XDC;
    float* xnext = bcT   + (size_t)BATCH * 128 * SEQ;
    float* hend  = xnext;                                 // [B*DI*NC, DS]
    float* h0buf = xnext + (size_t)BATCH * DI * NC * DS;  // [B*DI*NC, DS]

    // bf16 plane homes (all lifetimes disjoint on the serial stream):
    ushort_t* sh  = (ushort_t*)uT;
    ushort_t* sl  = sh  + (size_t)MROWS * DM;
    ushort_t* wih = (ushort_t*)(dtT + (size_t)MROWS * DM);
    ushort_t* wil = wih + (size_t)2 * DI * DM;
    ushort_t* uh  = (ushort_t*)dtT;
    ushort_t* ul  = uh  + (size_t)MROWS * DI;
    ushort_t* wxh = (ushort_t*)bcT;
    ushort_t* wxl = wxh + (size_t)256 * DI;
    ushort_t* woh = (ushort_t*)xdbl;
    ushort_t* wol = woh + (size_t)DM * DI;
    ushort_t* yh  = (ushort_t*)xnext;
    ushort_t* yl  = (ushort_t*)(dtT + (size_t)MROWS * DM);

    for (int i = 0; i < DEPTH; i++) {
        const float* Wi_l   = Wi   + (size_t)i * 2 * DI * DM;
        const float* cw_l   = cw   + (size_t)i * DI * DC;
        const float* cb_l   = cb   + (size_t)i * DI;
        const float* Wx_l   = Wx   + (size_t)i * XDC * DI;
        const float* Wdt_l  = Wdt  + (size_t)i * DI * DTR;
        const float* bdt_l  = bdt  + (size_t)i * DI;
        const float* Alog_l = Alog + (size_t)i * DI * DS;
        const float* Dsk_l  = Dsk  + (size_t)i * DI;
        const float* Wo_l   = Wo   + (size_t)i * DM * DI;

        // 1. input planes
        if (i == 0)
            split_bf16<<<(size_t)MROWS * DM / 1024, 256, 0, stream>>>(x, sh, sl);
        split_bf16<<<(size_t)2 * DI * DM / 1024, 256, 0, stream>>>(Wi_l, wih, wil);
        // 2. xz = src @ Wi^T
        gemm_mfma<<<dim3(2 * DI / 128, MROWS / 128), 256, 0, stream>>>(
            sh, sl, wih, wil, xz, 2 * DI, DM, DM, DM, nullptr, nullptr);
        // 3. u = silu(conv(xz[:, :DI]))
        conv_silu_T2<<<dim3(DI / 64, SEQ / 64, BATCH), 256, 0, stream>>>(
            xz, cw_l, cb_l, uT, uh, ul);
        // 4. Wx planes
        split_bf16<<<(size_t)XDC * DI / 1024, 256, 0, stream>>>(Wx_l, wxh, wxl);
        // 5. xdbl = u @ Wx^T
        gemm_mfma<<<dim3((XDC + 127) / 128, MROWS / 128), 256, 0, stream>>>(
            uh, ul, wxh, wxl, xdbl, XDC, DI, DI, DI, nullptr, nullptr);
        // 6. B/C -> lane-interleaved bc4 layout
        trans_bc_i4<<<dim3(2, SEQ / 64, BATCH), 256, 0, stream>>>(
            xdbl, (float4*)bcT);
        // 7. dtT = softplus(Wdt @ xdbl_dt^T + bdt)
        gemm_dt_T<<<dim3(SEQ / 128, DI / 128, BATCH), 256, 0, stream>>>(
            Wdt_l, xdbl, bdt_l, dtT);
        // 8. truncated-backward chunk-end states
        scan_tail<<<(BATCH * DI * NC) / 4, 256, 0, stream>>>(
            dtT, uT, (const float4*)bcT, Alog_l, hend);
        // 9. cross-chunk combine
        scan_phase2<<<(BATCH * DI) / 4, 256, 0, stream>>>(
            dtT, Alog_l, hend, h0buf);
        // 10. dual-chunk full scan; writes s into xz x-half (mapped)
        scan_phase3_d<<<(BATCH * DI * NC) / 8, 256, 0, stream>>>(
            dtT, uT, (const float4*)bcT, Alog_l, h0buf, xz);
        // 11. fused gate + split
        gate_split_T<<<dim3(DI / 64, SEQ / 64, BATCH), 256, 0, stream>>>(
            xz, uT, Dsk_l, yh, yl);
        // 12. Wo planes
        split_bf16<<<(size_t)DM * DI / 1024, 256, 0, stream>>>(Wo_l, woh, wol);
        // 13. out = y @ Wo^T
        if (i == DEPTH - 1)
            gemm_mfma<<<dim3(DM / 128, MROWS / 128), 256, 0, stream>>>(
                yh, yl, woh, wol, out, DM, DI, DI, DI, nullptr, nullptr);
        else
            gemm_mfma<<<dim3(DM / 128, MROWS / 128), 256, 0, stream>>>(
                yh, yl, woh, wol, xz /*unused*/, DM, DI, DI, DI, sh, sl);
    }
}

// Round 4
// 1421.305 us; speedup vs baseline: 1.1451x; 1.0352x over previous
//
#include <hip/hip_runtime.h>
#include <hip/hip_bf16.h>
#include <math.h>

// Problem constants (MambaStack reference)
#define DEPTH   2
#define DM      768      // d_model
#define DS      64       // d_state
#define DC      4        // d_conv
#define DI      1536     // d_inner
#define DTR     48       // dt_rank
#define BATCH   4
#define SEQ     2048
#define MROWS   (BATCH*SEQ)          // 8192
#define XDC     (DTR + 2*DS)         // 176 (xdbl cols)
#define NC      8                    // scan chunks
#define TCH     (SEQ/NC)             // 256 timesteps per chunk
#define LOG2E   1.44269504088896f

typedef __attribute__((ext_vector_type(8))) short bf16x8;
typedef __attribute__((ext_vector_type(4))) float f32x4;
typedef unsigned short ushort_t;
#define GAS __attribute__((address_space(1)))
#define LAS __attribute__((address_space(3)))

__device__ __forceinline__ float silu_fast(float x) {
    return x / (1.f + __expf(-x));
}
__device__ __forceinline__ float softplus_acc(float x) {
    return x > 20.f ? x : log1pf(expf(x));
}

// Split fp32 -> (hi, lo) bf16 pair, both RNE.  hi+lo represents f to ~2^-17.
__device__ __forceinline__ void bf16_split(float f, ushort_t& h, ushort_t& l) {
    unsigned u = __float_as_uint(f);
    unsigned hr = u + 0x7FFF + ((u >> 16) & 1);
    h = (ushort_t)(hr >> 16);
    float lof = f - __uint_as_float((unsigned)h << 16);
    unsigned ul = __float_as_uint(lof);
    unsigned lr = ul + 0x7FFF + ((ul >> 16) & 1);
    l = (ushort_t)(lr >> 16);
}

// Contiguous fp32 array -> hi/lo bf16 planes.  n multiple of 1024.
__global__ __launch_bounds__(256) void split_bf16(
    const float* __restrict__ in, ushort_t* __restrict__ hi,
    ushort_t* __restrict__ lo)
{
    const size_t i = ((size_t)blockIdx.x * 256 + threadIdx.x) * 4;
    const float4 v = *(const float4*)(in + i);
    ushort4 h, l;
    bf16_split(v.x, h.x, l.x); bf16_split(v.y, h.y, l.y);
    bf16_split(v.z, h.z, l.z); bf16_split(v.w, h.w, l.w);
    *(ushort4*)(hi + i) = h;
    *(ushort4*)(lo + i) = l;
}

// ---------------- bf16x2-split MFMA GEMM ----------------
// C[M,N] = (Ah+Al) @ (Wh+Wl)^T, planes bf16, row strides ldA/ldW (elements).
// 128x128 tile, BK=32, 4 waves; 16x16x32 MFMA, 3 per tile (hh, hl, lh).
// Output modes:
//   bc4out != null (x_proj): cols [DTR, DTR+128) emitted as lane-interleaved
//     float4 quads directly into bc4 (fuses the old trans_bc_i4 kernel);
//     cols [0,DTR) stored fp32 into C (row stride N); cols >= 176 dropped.
//   Chi != null: bf16 hi/lo planes.   else: fp32 with col<N guard.
// XCD-aware bijective block remap (gridDim.y % 8 == 0 for all call sites):
//   each XCD owns a contiguous band of M-tiles -> A-panels XCD-L2-local.
__global__ __launch_bounds__(256, 2) void gemm_mfma(
    const ushort_t* __restrict__ Ah, const ushort_t* __restrict__ Al,
    const ushort_t* __restrict__ Wh, const ushort_t* __restrict__ Wl,
    float* __restrict__ C, int N, int K, int ldA, int ldW,
    ushort_t* __restrict__ Chi, ushort_t* __restrict__ Clo,
    float4* __restrict__ bc4out)
{
    __shared__ ushort_t lds[4][128 * 32];
    const int tid  = threadIdx.x;
    const int wave = tid >> 6, lane = tid & 63;

    int bx = blockIdx.x, by = blockIdx.y;
    {   // T1 bijective XCD swizzle (requires gridDim.y % 8 == 0: always 64 here)
        const int X   = gridDim.x;
        const int fid = by * X + bx;
        const int xcd = fid & 7;
        const int j   = fid >> 3;
        const int jX  = j / X;
        by = xcd * (gridDim.y >> 3) + jX;
        bx = j - jX * X;
    }
    const int bm0 = by * 128, bn0 = bx * 128;
    const int wm = (wave >> 1) * 64, wn = (wave & 1) * 64;

    const ushort_t* gp = (wave == 0) ? Ah : (wave == 1) ? Al : (wave == 2) ? Wh : Wl;
    const int ldg = (wave < 2) ? ldA : ldW;
    const int rb = (wave < 2) ? bm0 : bn0;
    const int srow = lane >> 2;           // 0..15
    const int skq  = (lane & 3) * 8;      // k offset in elements

    f32x4 acc[4][4];
#pragma unroll
    for (int i = 0; i < 4; i++)
#pragma unroll
        for (int j = 0; j < 4; j++) acc[i][j] = (f32x4){0.f, 0.f, 0.f, 0.f};

    const int lm  = lane & 15;
    const int kg8 = (lane >> 4) * 8;

    for (int k0 = 0; k0 < K; k0 += 32) {
#pragma unroll
        for (int j = 0; j < 8; j++) {
            const ushort_t* ga = gp + (size_t)(rb + j * 16 + srow) * ldg + k0 + skq;
            __builtin_amdgcn_global_load_lds(
                (const GAS unsigned*)ga, (LAS unsigned*)&lds[wave][j * 512], 16, 0, 0);
        }
        __syncthreads();

        bf16x8 ah[4], al[4], bh[4], bl[4];
#pragma unroll
        for (int i = 0; i < 4; i++) {
            const int ar = (wm + i * 16 + lm) * 32 + kg8;
            ah[i] = *(const bf16x8*)&lds[0][ar];
            al[i] = *(const bf16x8*)&lds[1][ar];
            const int br = (wn + i * 16 + lm) * 32 + kg8;
            bh[i] = *(const bf16x8*)&lds[2][br];
            bl[i] = *(const bf16x8*)&lds[3][br];
        }
#pragma unroll
        for (int mi = 0; mi < 4; mi++)
#pragma unroll
            for (int ni = 0; ni < 4; ni++) {
                f32x4 t = acc[mi][ni];
                t = __builtin_amdgcn_mfma_f32_16x16x32_bf16(al[mi], bh[ni], t, 0, 0, 0);
                t = __builtin_amdgcn_mfma_f32_16x16x32_bf16(ah[mi], bl[ni], t, 0, 0, 0);
                t = __builtin_amdgcn_mfma_f32_16x16x32_bf16(ah[mi], bh[ni], t, 0, 0, 0);
                acc[mi][ni] = t;
            }
        __syncthreads();
    }

#pragma unroll
    for (int mi = 0; mi < 4; mi++)
#pragma unroll
        for (int ni = 0; ni < 4; ni++) {
            const int rowb = bm0 + wm + mi * 16 + (lane >> 4) * 4;  // mult of 4
            const int colg = bn0 + wn + ni * 16 + lm;
            if (bc4out) {
                // x_proj fused epilogue
                if (colg >= DTR && colg < DTR + 2 * DS) {
                    const f32x4 a = acc[mi][ni];
                    bc4out[(size_t)(rowb >> 2) * 128 + (colg - DTR)] =
                        make_float4(a[0], a[1], a[2], a[3]);
                } else if (colg < DTR) {
#pragma unroll
                    for (int r = 0; r < 4; r++)
                        C[(size_t)(rowb + r) * N + colg] = acc[mi][ni][r];
                }
            } else if (Chi) {
#pragma unroll
                for (int r = 0; r < 4; r++) {
                    ushort_t h, l;
                    bf16_split(acc[mi][ni][r], h, l);
                    Chi[(size_t)(rowb + r) * N + colg] = h;
                    Clo[(size_t)(rowb + r) * N + colg] = l;
                }
            } else {
#pragma unroll
                for (int r = 0; r < 4; r++)
                    if (colg < N)
                        C[(size_t)(rowb + r) * N + colg] = acc[mi][ni][r];
            }
        }
}

// dt GEMM, transposed output: dtT[(b*DI+d)*SEQ + t] =
//   softplus(sum_k Wdt[d][k] * xdbl[b*SEQ+t][k] + bias[d]).
__global__ __launch_bounds__(256, 2) void gemm_dt_T(
    const float* __restrict__ Wdt, const float* __restrict__ xdbl,
    const float* __restrict__ bias, float* __restrict__ dtT)
{
    __shared__ float As[8][132];
    __shared__ float Bs[8][132];
    const int tid = threadIdx.x;
    const int bd0 = blockIdx.y * 128;   // d tile
    const int bt0 = blockIdx.x * 128;   // t tile
    const int b   = blockIdx.z;
    const int tx = tid & 15;            // t group
    const int ty = tid >> 4;            // d group
    const int lrow = tid >> 1;
    const int lk4  = (tid & 1) * 4;

    float acc[8][8];
#pragma unroll
    for (int i = 0; i < 8; i++)
#pragma unroll
        for (int j = 0; j < 8; j++) acc[i][j] = 0.f;

    for (int k0 = 0; k0 < DTR; k0 += 8) {
        const float4 av = *(const float4*)(Wdt + (size_t)(bd0 + lrow) * DTR + k0 + lk4);
        const float4 wv = *(const float4*)(xdbl + ((size_t)b * SEQ + bt0 + lrow) * XDC + k0 + lk4);
        __syncthreads();
        As[lk4 + 0][lrow] = av.x; As[lk4 + 1][lrow] = av.y;
        As[lk4 + 2][lrow] = av.z; As[lk4 + 3][lrow] = av.w;
        Bs[lk4 + 0][lrow] = wv.x; Bs[lk4 + 1][lrow] = wv.y;
        Bs[lk4 + 2][lrow] = wv.z; Bs[lk4 + 3][lrow] = wv.w;
        __syncthreads();
#pragma unroll
        for (int kk = 0; kk < 8; kk++) {
            const float4 a0 = *(const float4*)&As[kk][ty * 8];
            const float4 a1 = *(const float4*)&As[kk][ty * 8 + 4];
            const float4 b0 = *(const float4*)&Bs[kk][tx * 8];
            const float4 b1 = *(const float4*)&Bs[kk][tx * 8 + 4];
            const float ar[8] = {a0.x, a0.y, a0.z, a0.w, a1.x, a1.y, a1.z, a1.w};
            const float br[8] = {b0.x, b0.y, b0.z, b0.w, b1.x, b1.y, b1.z, b1.w};
#pragma unroll
            for (int i = 0; i < 8; i++)
#pragma unroll
                for (int j = 0; j < 8; j++)
                    acc[i][j] = fmaf(ar[i], br[j], acc[i][j]);
        }
    }

#pragma unroll
    for (int i = 0; i < 8; i++) {
        const int d = bd0 + ty * 8 + i;
        const float bb = bias[d];
#pragma unroll
        for (int j4 = 0; j4 < 8; j4 += 4) {
            float4 v = make_float4(acc[i][j4], acc[i][j4 + 1], acc[i][j4 + 2], acc[i][j4 + 3]);
            v.x = softplus_acc(v.x + bb);
            v.y = softplus_acc(v.y + bb);
            v.z = softplus_acc(v.z + bb);
            v.w = softplus_acc(v.w + bb);
            *(float4*)(dtT + ((size_t)b * DI + d) * SEQ + bt0 + tx * 8 + j4) = v;
        }
    }
}

// Depthwise causal conv (K=4) + SiLU -> uT [b][d][t] fp32 AND row-major
// bf16 hi/lo planes (for the x_proj MFMA GEMM).
__global__ __launch_bounds__(256) void conv_silu_T2(
    const float* __restrict__ xz, const float* __restrict__ cw,
    const float* __restrict__ cb, float* __restrict__ uT,
    ushort_t* __restrict__ uh, ushort_t* __restrict__ ul)
{
    __shared__ float tin[67][65];
    __shared__ float ttr[64][65];
    const int tid = threadIdx.x;
    const int d0 = blockIdx.x * 64, t0 = blockIdx.y * 64, b = blockIdx.z;
    const int cl = tid & 63, q = tid >> 6;

    for (int r = q; r < 67; r += 4) {
        const int t = t0 - 3 + r;
        float v = 0.f;
        if (t >= 0) v = xz[((size_t)b * SEQ + t) * (2 * DI) + d0 + cl];
        tin[r][cl] = v;
    }
    __syncthreads();

    const float4 w = ((const float4*)cw)[d0 + cl];
    const float bb = cb[d0 + cl];
#pragma unroll
    for (int i = 0; i < 16; i++) {
        const int t = q * 16 + i;
        float a = bb;
        a = fmaf(tin[t + 0][cl], w.x, a);
        a = fmaf(tin[t + 1][cl], w.y, a);
        a = fmaf(tin[t + 2][cl], w.z, a);
        a = fmaf(tin[t + 3][cl], w.w, a);
        a = silu_fast(a);
        ttr[cl][t] = a;
        ushort_t h, l;
        bf16_split(a, h, l);
        const size_t row = (size_t)b * SEQ + t0 + t;
        uh[row * DI + d0 + cl] = h;          // coalesced in d
        ul[row * DI + d0 + cl] = l;
    }
    __syncthreads();
#pragma unroll
    for (int i = 0; i < 16; i++) {
        const int d = q * 16 + i;
        uT[((size_t)b * DI + d0 + d) * SEQ + t0 + cl] = ttr[d][cl];  // coalesced in t
    }
}

// ---------------- Chunked selective scan ----------------
// s output lives in the dead xz x-half via the linear map
//   addr(L) = (L/1536)*3072 + L%1536,  L = bd*SEQ + t.

#define LOAD3(DT, UU, BB_, TB)                                         \
    _Pragma("unroll")                                                  \
    for (int g = 0; g < 4; g++) {                                      \
        DT[g]  = *(const float4*)(dtp + (TB) + 4 * g);                 \
        UU[g]  = *(const float4*)(up + (TB) + 4 * g);                  \
        BB_[g] = Bp[(size_t)((TB) / 4 + g) * 128];                     \
    }

#define LOAD4S(DT, UU, BB_, CC_, TB)                                   \
    _Pragma("unroll")                                                  \
    for (int g = 0; g < 4; g++) {                                      \
        DT[g]  = *(const float4*)(dtp + (TB) + 4 * g);                 \
        UU[g]  = *(const float4*)(up + (TB) + 4 * g);                  \
        BB_[g] = Bp[(size_t)((TB) / 4 + g) * 128];                     \
        CC_[g] = Cp[(size_t)((TB) / 4 + g) * 128];                     \
    }

#define P3_BLOCK(DT, UU, BB_, CC_, TBASE)                                                          \
    {                                                                                              \
        float p[16];                                                                               \
        _Pragma("unroll")                                                                          \
        for (int g = 0; g < 4; g++) {                                                              \
            h = fmaf(__builtin_amdgcn_exp2f(DT[g].x * An), h, (DT[g].x * UU[g].x) * BB_[g].x); p[4*g+0] = h * CC_[g].x; \
            h = fmaf(__builtin_amdgcn_exp2f(DT[g].y * An), h, (DT[g].y * UU[g].y) * BB_[g].y); p[4*g+1] = h * CC_[g].y; \
            h = fmaf(__builtin_amdgcn_exp2f(DT[g].z * An), h, (DT[g].z * UU[g].z) * BB_[g].z); p[4*g+2] = h * CC_[g].z; \
            h = fmaf(__builtin_amdgcn_exp2f(DT[g].w * An), h, (DT[g].w * UU[g].w) * BB_[g].w); p[4*g+3] = h * CC_[g].w; \
        }                                                                                          \
        _Pragma("unroll")                                                                          \
        for (int i = 0; i < 16; i++) slab[i * 65 + lane] = p[i];                                   \
        float s = 0.f;                                                                             \
        _Pragma("unroll")                                                                          \
        for (int j = 0; j < 16; j++) s += slab[tt * 65 + seg * 16 + j];                            \
        s += __shfl_xor(s, 16, 64);                                                                \
        s += __shfl_xor(s, 32, 64);                                                                \
        if (lane < 16) sp[(TBASE) + tt] = s;                                                       \
    }

// Truncated-backward chunk-end state:
//   hend = sum_t exp2(An * R_t) * dt_t*u_t*B_t,   R_t = suffix-sum of dt.
// All An < 0 and the weights decay monotonically, so once every lane's
// weight underflows 2^-30 the remaining (earlier) terms are numerically
// irrelevant.  Typical stop: ~32 of 256 steps; worst case = full chunk.
__global__ __launch_bounds__(256, 2) void scan_tail(
    const float* __restrict__ dtT, const float* __restrict__ uT,
    const float4* __restrict__ bc4, const float* __restrict__ A_log,
    float* __restrict__ hend)
{
    const int wid  = __builtin_amdgcn_readfirstlane(
                        (int)((blockIdx.x * 256 + threadIdx.x) >> 6));
    const int lane = threadIdx.x & 63;
    const int c  = wid & (NC - 1);
    const int bd = wid >> 3;
    const int b  = bd / DI;
    const int d  = bd - b * DI;

    const float An = -expf(A_log[d * DS + lane]) * LOG2E;
    const float* dtp = dtT + (size_t)bd * SEQ + c * TCH;
    const float* up  = uT  + (size_t)bd * SEQ + c * TCH;
    const float4* Bp = bc4 + ((size_t)b * (SEQ / 4) + c * (TCH / 4)) * 128 + lane;

    float h = 0.f, r = 0.f;
    for (int tb = TCH - 16; tb >= 0; tb -= 16) {
        float4 dt4[4], u4[4], B4[4];
#pragma unroll
        for (int g = 0; g < 4; g++) {
            dt4[g] = *(const float4*)(dtp + tb + 4 * g);
            u4[g]  = *(const float4*)(up  + tb + 4 * g);
            B4[g]  = Bp[(size_t)(tb / 4 + g) * 128];
        }
#pragma unroll
        for (int g = 3; g >= 0; g--) {
            h = fmaf(__builtin_amdgcn_exp2f(An * r), (dt4[g].w * u4[g].w) * B4[g].w, h); r += dt4[g].w;
            h = fmaf(__builtin_amdgcn_exp2f(An * r), (dt4[g].z * u4[g].z) * B4[g].z, h); r += dt4[g].z;
            h = fmaf(__builtin_amdgcn_exp2f(An * r), (dt4[g].y * u4[g].y) * B4[g].y, h); r += dt4[g].y;
            h = fmaf(__builtin_amdgcn_exp2f(An * r), (dt4[g].x * u4[g].x) * B4[g].x, h); r += dt4[g].x;
        }
        if (__all(An * r < -30.f)) break;   // all remaining weights < 2^-30
    }
    hend[(size_t)wid * DS + lane] = h;
}

// Cross-chunk combine (computes per-chunk dt sums internally).
__global__ __launch_bounds__(256) void scan_phase2(
    const float* __restrict__ dtT, const float* __restrict__ A_log,
    const float* __restrict__ hend, float* __restrict__ h0out)
{
    const int bd   = (blockIdx.x * 256 + threadIdx.x) >> 6;
    const int lane = threadIdx.x & 63;
    const int d    = bd % DI;

    const float* dtp = dtT + (size_t)bd * SEQ + lane * 32;
    float s = 0.f;
#pragma unroll
    for (int g = 0; g < 8; g++) {
        const float4 v = *(const float4*)(dtp + 4 * g);
        s += (v.x + v.y) + (v.z + v.w);
    }
    s += __shfl_xor(s, 1, 64);
    s += __shfl_xor(s, 2, 64);
    s += __shfl_xor(s, 4, 64);   // lanes 8c..8c+7 all hold chunk-c sum

    const float An = -expf(A_log[d * DS + lane]) * LOG2E;
    float h = 0.f;
#pragma unroll
    for (int c = 0; c < NC; c++) {
        const float sdt = __shfl(s, 8 * c, 64);
        const size_t off = ((size_t)bd * NC + c) * DS + lane;
        h0out[off] = h;
        h = fmaf(__builtin_amdgcn_exp2f(An * sdt), h, hend[off]);
    }
}

__global__ __launch_bounds__(256, 2) void scan_phase3(
    const float* __restrict__ dtT, const float* __restrict__ uT,
    const float4* __restrict__ bc4, const float* __restrict__ A_log,
    const float* __restrict__ hin, float* __restrict__ sX)
{
    __shared__ float red[4][16 * 65];
    const int wid  = __builtin_amdgcn_readfirstlane(
                        (int)((blockIdx.x * 256 + threadIdx.x) >> 6));
    const int lane = threadIdx.x & 63;
    const int c  = wid & (NC - 1);
    const int bd = wid >> 3;
    const int b  = bd / DI;
    const int d  = bd - b * DI;

    const float An = -expf(A_log[d * DS + lane]) * LOG2E;
    const float* dtp = dtT + (size_t)bd * SEQ + c * TCH;
    const float* up  = uT  + (size_t)bd * SEQ + c * TCH;
    const float4* Bp = bc4 + ((size_t)b * (SEQ / 4) + c * (TCH / 4)) * 128 + lane;
    const float4* Cp = Bp + 64;
    const size_t L0 = (size_t)bd * SEQ + c * TCH;
    float* sp = sX + (L0 / 1536) * 3072 + (L0 % 1536);
    float* slab = &red[threadIdx.x >> 6][0];
    const int tt = lane & 15, seg = lane >> 4;

    float4 dA4[4], uA4[4], BA4[4], CA4[4], dB4[4], uB4[4], BB4[4], CB4[4];
    LOAD4S(dA4, uA4, BA4, CA4, 0);

    float h = hin[(size_t)wid * DS + lane];
    for (int tb = 0; tb < TCH; tb += 32) {
        LOAD4S(dB4, uB4, BB4, CB4, tb + 16);
        P3_BLOCK(dA4, uA4, BA4, CA4, tb);
        LOAD4S(dA4, uA4, BA4, CA4, tb + 32);   // final iter overreads (safe)
        P3_BLOCK(dB4, uB4, BB4, CB4, tb + 16);
    }
}

// Fused gate + transpose + bf16-split:
//   y = (s + D*u) * silu(z), emitted directly as row-major bf16 planes yh/yl.
__global__ __launch_bounds__(256) void gate_split_T(
    const float* __restrict__ xz, const float* __restrict__ uT,
    const float* __restrict__ Dskip,
    ushort_t* __restrict__ yh, ushort_t* __restrict__ yl)
{
    __shared__ float zt[64][65];   // [t][d]
    __shared__ float yt[64][65];   // [d][t]
    const int tid = threadIdx.x;
    const int d0 = blockIdx.x * 64, t0 = blockIdx.y * 64, b = blockIdx.z;
    const int cl = tid & 63, q = tid >> 6;
#pragma unroll
    for (int i = 0; i < 16; i++) {
        const int r = q * 16 + i;
        zt[r][cl] = xz[((size_t)b * SEQ + t0 + r) * (2 * DI) + DI + d0 + cl];
    }
    __syncthreads();
#pragma unroll
    for (int i = 0; i < 16; i++) {
        const int dd = q * 16 + i;
        const size_t Lrow = ((size_t)b * DI + d0 + dd) * SEQ + t0;
        const float s = xz[(Lrow / 1536) * 3072 + (Lrow % 1536) + cl];
        const float u = uT[Lrow + cl];
        const float Dd = Dskip[d0 + dd];   // wave-uniform
        yt[dd][cl] = (s + Dd * u) * silu_fast(zt[cl][dd]);
    }
    __syncthreads();
#pragma unroll
    for (int i = 0; i < 16; i++) {
        const int t = q * 16 + i;
        ushort_t h, l;
        bf16_split(yt[cl][t], h, l);
        const size_t row = (size_t)b * SEQ + t0 + t;
        yh[row * DI + d0 + cl] = h;        // coalesced in d
        yl[row * DI + d0 + cl] = l;
    }
}

extern "C" void kernel_launch(void* const* d_in, const int* in_sizes, int n_in,
                              void* d_out, int out_size, void* d_ws, size_t ws_size,
                              hipStream_t stream) {
    (void)in_sizes; (void)n_in; (void)out_size; (void)ws_size;
    const float* x    = (const float*)d_in[0];
    const float* Wi   = (const float*)d_in[1];
    const float* cw   = (const float*)d_in[2];
    const float* cb   = (const float*)d_in[3];
    const float* Wx   = (const float*)d_in[4];
    const float* Wdt  = (const float*)d_in[5];
    const float* bdt  = (const float*)d_in[6];
    const float* Alog = (const float*)d_in[7];
    const float* Dsk  = (const float*)d_in[8];
    const float* Wo   = (const float*)d_in[9];
    float* out = (float*)d_out;

    // Workspace (fp32) regions:
    float* xz    = (float*)d_ws;                          // [MROWS, 3072]
    float* uT    = xz    + (size_t)MROWS * (2 * DI);
    float* dtT   = uT    + (size_t)MROWS * DI;
    float* xdbl  = dtT   + (size_t)MROWS * DI;
    float* bcT   = xdbl  + (size_t)MROWS * XDC;           // bc4 interleaved (written by x_proj GEMM)
    float* xnext = bcT   + (size_t)BATCH * 128 * SEQ;
    float* hend  = xnext;                                 // [B*DI*NC, DS]
    float* h0buf = xnext + (size_t)BATCH * DI * NC * DS;  // [B*DI*NC, DS]

    // bf16 plane homes (all lifetimes disjoint on the serial stream):
    ushort_t* sh  = (ushort_t*)uT;
    ushort_t* sl  = sh  + (size_t)MROWS * DM;
    ushort_t* wih = (ushort_t*)(dtT + (size_t)MROWS * DM);
    ushort_t* wil = wih + (size_t)2 * DI * DM;
    ushort_t* uh  = (ushort_t*)dtT;
    ushort_t* ul  = uh  + (size_t)MROWS * DI;
    ushort_t* wxh = (ushort_t*)xnext;                     // [256(pad), DI] x2 in xnext
    ushort_t* wxl = wxh + (size_t)256 * DI;               //   (dead before scan: hend overwrites)
    ushort_t* woh = (ushort_t*)xdbl;
    ushort_t* wol = woh + (size_t)DM * DI;
    ushort_t* yh  = (ushort_t*)xnext;
    ushort_t* yl  = (ushort_t*)(dtT + (size_t)MROWS * DM);

    for (int i = 0; i < DEPTH; i++) {
        const float* Wi_l   = Wi   + (size_t)i * 2 * DI * DM;
        const float* cw_l   = cw   + (size_t)i * DI * DC;
        const float* cb_l   = cb   + (size_t)i * DI;
        const float* Wx_l   = Wx   + (size_t)i * XDC * DI;
        const float* Wdt_l  = Wdt  + (size_t)i * DI * DTR;
        const float* bdt_l  = bdt  + (size_t)i * DI;
        const float* Alog_l = Alog + (size_t)i * DI * DS;
        const float* Dsk_l  = Dsk  + (size_t)i * DI;
        const float* Wo_l   = Wo   + (size_t)i * DM * DI;

        // 1. input planes
        if (i == 0)
            split_bf16<<<(size_t)MROWS * DM / 1024, 256, 0, stream>>>(x, sh, sl);
        split_bf16<<<(size_t)2 * DI * DM / 1024, 256, 0, stream>>>(Wi_l, wih, wil);
        // 2. xz = src @ Wi^T
        gemm_mfma<<<dim3(2 * DI / 128, MROWS / 128), 256, 0, stream>>>(
            sh, sl, wih, wil, xz, 2 * DI, DM, DM, DM, nullptr, nullptr, nullptr);
        // 3. u = silu(conv(xz[:, :DI]))
        conv_silu_T2<<<dim3(DI / 64, SEQ / 64, BATCH), 256, 0, stream>>>(
            xz, cw_l, cb_l, uT, uh, ul);
        // 4. Wx planes (xnext region; pad rows 176..255 arbitrary garbage —
        //    their MFMA columns are >= 176 and never stored)
        split_bf16<<<(size_t)XDC * DI / 1024, 256, 0, stream>>>(Wx_l, wxh, wxl);
        // 5. xdbl = u @ Wx^T ; B/C columns emitted directly as bc4 (fused
        //    trans_bc), dt-rank columns as fp32 rows into xdbl
        gemm_mfma<<<dim3((XDC + 127) / 128, MROWS / 128), 256, 0, stream>>>(
            uh, ul, wxh, wxl, xdbl, XDC, DI, DI, DI, nullptr, nullptr,
            (float4*)bcT);
        // 6. dtT = softplus(Wdt @ xdbl_dt^T + bdt)
        gemm_dt_T<<<dim3(SEQ / 128, DI / 128, BATCH), 256, 0, stream>>>(
            Wdt_l, xdbl, bdt_l, dtT);
        // 7. truncated-backward chunk-end states (overwrites wxh/wxl, dead)
        scan_tail<<<(BATCH * DI * NC) / 4, 256, 0, stream>>>(
            dtT, uT, (const float4*)bcT, Alog_l, hend);
        // 8. cross-chunk combine
        scan_phase2<<<(BATCH * DI) / 4, 256, 0, stream>>>(
            dtT, Alog_l, hend, h0buf);
        // 9. full scan with outputs; writes s into xz x-half (mapped)
        scan_phase3<<<(BATCH * DI * NC) / 4, 256, 0, stream>>>(
            dtT, uT, (const float4*)bcT, Alog_l, h0buf, xz);
        // 10. fused gate + split
        gate_split_T<<<dim3(DI / 64, SEQ / 64, BATCH), 256, 0, stream>>>(
            xz, uT, Dsk_l, yh, yl);
        // 11. Wo planes
        split_bf16<<<(size_t)DM * DI / 1024, 256, 0, stream>>>(Wo_l, woh, wol);
        // 12. out = y @ Wo^T
        if (i == DEPTH - 1)
            gemm_mfma<<<dim3(DM / 128, MROWS / 128), 256, 0, stream>>>(
                yh, yl, woh, wol, out, DM, DI, DI, DI, nullptr, nullptr, nullptr);
        else
            gemm_mfma<<<dim3(DM / 128, MROWS / 128), 256, 0, stream>>>(
                yh, yl, woh, wol, xz /*unused*/, DM, DI, DI, DI, sh, sl, nullptr);
    }
}